// Round 15
// baseline (1014.280 us; speedup 1.0000x reference)
//
#include <hip/hip_runtime.h>
#include <hip/hip_bf16.h>
#include <math.h>

// ---------------------------------------------------------------------------
// DGSR layer, MI355X. H = 128 fixed.
//   0. zero_kernel: zero degree arrays
//   1. CSR build: histogram -> 3-kernel scan -> scatter of int2 (partner,eid)
//   2. gemm6: fused 6 projections -> interleaved bf16 tables (chunk q =
//      {elems 4q..4q+3, 64+4q..64+4q+3})
//   3. gather_u: 16-lane group per user (4/wave), UNROLL 1 + record
//      prefetch, hoisted rows kept PACKED bf16 (VGPR<=64 -> 8 waves/SIMD).
//      All 5 logit dots in-reg; writes x24[eid]=(x2,x4).
//   4. gather_i: 16-lane group per item, unroll 1 + record/x prefetch,
//      pure streaming accumulate. VGPR<=64.
// exp without max-subtraction (logits ~N(0,1.4)). No f32 atomics anywhere.
// ---------------------------------------------------------------------------

#define WB 1024  // elements per scan block

typedef float fvec4 __attribute__((ext_vector_type(4)));

__device__ __forceinline__ float4 nt_load4(const float* p) {
    fvec4 v = __builtin_nontemporal_load((const fvec4*)p);
    return make_float4(v.x, v.y, v.z, v.w);
}
__device__ __forceinline__ float dot4(float4 a, float4 b) {
    return a.x * b.x + a.y * b.y + a.z * b.z + a.w * b.w;
}
// unpack 8 bf16 (uint4 = one interleaved chunk) -> lo4 (elems 4q..) hi4 (64+4q..)
__device__ __forceinline__ void bfu(uint4 v, float4& lo, float4& hi) {
    lo.x = __uint_as_float(v.x << 16);
    lo.y = __uint_as_float(v.x & 0xFFFF0000u);
    lo.z = __uint_as_float(v.y << 16);
    lo.w = __uint_as_float(v.y & 0xFFFF0000u);
    hi.x = __uint_as_float(v.z << 16);
    hi.y = __uint_as_float(v.z & 0xFFFF0000u);
    hi.z = __uint_as_float(v.w << 16);
    hi.w = __uint_as_float(v.w & 0xFFFF0000u);
}
__device__ __forceinline__ unsigned rne16(float f) {
    unsigned u = __float_as_uint(f);
    return (u + 0x7FFFu + ((u >> 16) & 1u)) >> 16;
}
__device__ __forceinline__ unsigned pack2(float a, float b) {
    return rne16(a) | (rne16(b) << 16);
}

// ----------------------- zeroing -------------------------------------------
__global__ __launch_bounds__(256) void zero_kernel(int* __restrict__ p, int n)
{
    int i = blockIdx.x * 256 + threadIdx.x;
    if (i < n) p[i] = 0;
}

// ----------------------- fused 6x GEMM -> interleaved bf16 tables -----------
struct Gemm6Desc {
    const float* X[6];
    const float* W[6];
    unsigned short* O[6];
    const int*   g[6];
    int          ostride[6];
    int          nrows[6];
};

__global__ __launch_bounds__(256) void gemm6_kernel(Gemm6Desc d)
{
    __shared__ float Xl[64 * 32];
    __shared__ float Wl[128 * 32];
    const int j6 = blockIdx.y;
    const float* __restrict__ X = d.X[j6];
    const float* __restrict__ W = d.W[j6];
    unsigned short* __restrict__ O = d.O[j6];
    const int* __restrict__ gidx = d.g[j6];
    const int ostride = d.ostride[j6];
    const int nrows   = d.nrows[j6];

    const int t  = threadIdx.x;
    const int tx = t & 15;
    const int ty = t >> 4;
    const int brow = blockIdx.x * 64;
    if (brow >= nrows) return;

    float acc[4][8];
#pragma unroll
    for (int j = 0; j < 4; ++j)
#pragma unroll
        for (int i = 0; i < 8; ++i) acc[j][i] = 0.f;

    for (int k0 = 0; k0 < 128; k0 += 32) {
        __syncthreads();
#pragma unroll
        for (int u = 0; u < 2; ++u) {
            int idx4 = t + u * 256;
            int r  = idx4 >> 3;
            int k4 = idx4 & 7;
            int row = brow + r;
            float4 v = make_float4(0.f, 0.f, 0.f, 0.f);
            if (row < nrows) {
                int g = gidx ? gidx[row] : row;
                v = *(const float4*)(X + (size_t)g * 128 + k0 + k4 * 4);
            }
            int sw = k4 ^ ((r >> 3) & 7);
            *(float4*)(Xl + r * 32 + sw * 4) = v;
        }
#pragma unroll
        for (int u = 0; u < 4; ++u) {
            int idx4 = t + u * 256;
            int c  = idx4 >> 3;
            int k4 = idx4 & 7;
            float4 v = *(const float4*)(W + (size_t)c * 128 + k0 + k4 * 4);
            int sw = k4 ^ ((c >> 3) & 7);
            *(float4*)(Wl + c * 32 + sw * 4) = v;
        }
        __syncthreads();
#pragma unroll
        for (int k4 = 0; k4 < 8; ++k4) {
            float4 xv[4], wv[8];
#pragma unroll
            for (int j = 0; j < 4; ++j) {
                int r = ty * 4 + j;
                xv[j] = *(const float4*)(Xl + r * 32 + ((k4 ^ ((r >> 3) & 7)) * 4));
            }
#pragma unroll
            for (int i = 0; i < 8; ++i) {
                int c = tx * 8 + i;
                wv[i] = *(const float4*)(Wl + c * 32 + ((k4 ^ ((c >> 3) & 7)) * 4));
            }
#pragma unroll
            for (int j = 0; j < 4; ++j)
#pragma unroll
                for (int i = 0; i < 8; ++i) {
                    acc[j][i] += xv[j].x * wv[i].x;
                    acc[j][i] += xv[j].y * wv[i].y;
                    acc[j][i] += xv[j].z * wv[i].z;
                    acc[j][i] += xv[j].w * wv[i].w;
                }
        }
    }
    const int base = (tx < 8) ? (16 * tx) : (16 * (tx - 8) + 4);
#pragma unroll
    for (int j = 0; j < 4; ++j) {
        int row = brow + ty * 4 + j;
        if (row < nrows) {
            unsigned short* op = O + (size_t)row * ostride;
            uint2 lo, hi;
            lo.x = pack2(acc[j][0], acc[j][1]);
            lo.y = pack2(acc[j][2], acc[j][3]);
            hi.x = pack2(acc[j][4], acc[j][5]);
            hi.y = pack2(acc[j][6], acc[j][7]);
            *(uint2*)(op + base)     = lo;
            *(uint2*)(op + base + 8) = hi;
        }
    }
}

// ----------------------- CSR build ------------------------------------------
__global__ __launch_bounds__(256) void hist_kernel(
    const int* __restrict__ ei, int E,
    int* __restrict__ deg_u, int* __restrict__ deg_i)
{
    int e = blockIdx.x * 256 + threadIdx.x;
    if (e < E) {
        atomicAdd(&deg_u[ei[e]], 1);
        atomicAdd(&deg_i[ei[E + e]], 1);
    }
}

__global__ __launch_bounds__(256) void scan_blocksums_kernel(
    const int* __restrict__ deg_u, int nu, int nbu,
    const int* __restrict__ deg_i, int ni,
    int* __restrict__ bsum)
{
    int b = blockIdx.x;
    const int* deg; int n; int base;
    if (b < nbu) { deg = deg_u; n = nu; base = b * WB; }
    else         { deg = deg_i; n = ni; base = (b - nbu) * WB; }
    int t = threadIdx.x;
    int s = 0;
#pragma unroll
    for (int j = 0; j < 4; ++j) {
        int i = base + t * 4 + j;
        if (i < n) s += deg[i];
    }
#pragma unroll
    for (int o = 32; o > 0; o >>= 1) s += __shfl_xor(s, o);
    __shared__ int wt[4];
    if ((t & 63) == 0) wt[t >> 6] = s;
    __syncthreads();
    if (t == 0) bsum[b] = wt[0] + wt[1] + wt[2] + wt[3];
}

__global__ void scan_partials_kernel(
    const int* __restrict__ bsum, int* __restrict__ bscan,
    int nbu, int nbi,
    int* __restrict__ off_u, int nu, int* __restrict__ off_i, int ni)
{
    if (threadIdx.x != 0) return;
    if (blockIdx.x == 0) {
        int c = 0;
        for (int b = 0; b < nbu; ++b) { bscan[b] = c; c += bsum[b]; }
        off_u[nu] = c;
    } else {
        int c = 0;
        for (int b = 0; b < nbi; ++b) { bscan[nbu + b] = c; c += bsum[nbu + b]; }
        off_i[ni] = c;
    }
}

__global__ __launch_bounds__(256) void scan_final_kernel(
    const int* __restrict__ deg_u, int nu, int nbu,
    const int* __restrict__ deg_i, int ni,
    const int* __restrict__ bscan,
    int* __restrict__ off_u, int* __restrict__ cur_u,
    int* __restrict__ off_i, int* __restrict__ cur_i)
{
    int b = blockIdx.x;
    const int* deg; int n; int base; int* off; int* cur;
    if (b < nbu) { deg = deg_u; n = nu; base = b * WB; off = off_u; cur = cur_u; }
    else         { deg = deg_i; n = ni; base = (b - nbu) * WB; off = off_i; cur = cur_i; }
    int t = threadIdx.x;
    int lane = t & 63, w = t >> 6;
    int v[4];
    int s = 0;
#pragma unroll
    for (int j = 0; j < 4; ++j) {
        int i = base + t * 4 + j;
        v[j] = (i < n) ? deg[i] : 0;
        s += v[j];
    }
    int inc = s;
#pragma unroll
    for (int o = 1; o < 64; o <<= 1) {
        int x = __shfl_up(inc, o);
        if (lane >= o) inc += x;
    }
    int excl = inc - s;
    __shared__ int wt[4];
    if (lane == 63) wt[w] = inc;
    __syncthreads();
    int wbase = 0;
    for (int j = 0; j < w; ++j) wbase += wt[j];
    int e = bscan[b] + wbase + excl;
#pragma unroll
    for (int j = 0; j < 4; ++j) {
        int i = base + t * 4 + j;
        if (i < n) { off[i] = e; cur[i] = e; }
        e += v[j];
    }
}

__global__ __launch_bounds__(256) void scatter_ids_kernel(
    const int* __restrict__ ei, int E,
    int* __restrict__ cur_u, int* __restrict__ cur_i,
    int2* __restrict__ eu_list, int2* __restrict__ ei_list)
{
    int e = blockIdx.x * 256 + threadIdx.x;
    if (e < E) {
        int u = ei[e], v = ei[E + e];
        int pu = atomicAdd(&cur_u[u], 1);
        eu_list[pu] = make_int2(v, e);   // (item, eid)
        int pi = atomicAdd(&cur_i[v], 1);
        ei_list[pi] = make_int2(u, e);   // (user, eid)
    }
}

// ----------------------- gather_u: 16-lane group/user, unroll 1, VGPR<=64 ---
__global__ __launch_bounds__(256, 8) void gather_u_kernel(
    const unsigned short* __restrict__ fusedU,   // [U,256] bf16 interleaved
    const unsigned short* __restrict__ fusedI,   // [I,256] bf16 interleaved
    const unsigned short* __restrict__ last_item,
    const unsigned short* __restrict__ last_user,
    const float* __restrict__ pVui, const float* __restrict__ pKiu,
    const int2* __restrict__ lst, const int* __restrict__ off_u,
    float2* __restrict__ x24,
    float* __restrict__ hLu, float* __restrict__ hSu, int U, float inv_sqrt_d)
{
    const int wv   = (int)(((size_t)blockIdx.x * blockDim.x + threadIdx.x) >> 6);
    const int lane = threadIdx.x & 63;
    const int g = lane >> 4;   // user group within wave
    const int q = lane & 15;   // chunk slot: elems {4q..4q+3, 64+4q..64+4q+3}
    const int uid = wv * 4 + g;
    if (uid >= U) return;

    // hoisted user rows kept PACKED (12 VGPR instead of 24)
    const uint4 umP = ((const uint4*)(fusedU    + (size_t)uid * 256))[q];
    const uint4 liP = ((const uint4*)(last_item + (size_t)uid * 128))[q];
    const uint4 luP = ((const uint4*)(last_user + (size_t)uid * 128))[q];

    float4 a1l = make_float4(0.f,0.f,0.f,0.f), a1h = make_float4(0.f,0.f,0.f,0.f);
    float4 a3l = make_float4(0.f,0.f,0.f,0.f), a3h = make_float4(0.f,0.f,0.f,0.f);
    float s1 = 0.f, s3 = 0.f;
    const int e0 = off_u[uid], e1 = off_u[uid + 1];

    int eA = e0;
    bool vA = eA < e1;
    int2 rA = vA ? lst[eA] : make_int2(0, 0);

    while (vA) {
        // prefetch next record
        const int eN = eA + 1;
        const bool vN = eN < e1;
        const int2 rN = vN ? lst[eN] : rA;

        const uint4* fIA = (const uint4*)(fusedI + (size_t)rA.x * 256);
        const float* pvA = pVui + (size_t)rA.y * 128;
        const float* pkA = pKiu + (size_t)rA.y * 128;

        uint4 iaP = fIA[q], ibP = fIA[16 + q];
        float4 pv0 = nt_load4(pvA + q * 4), pv1 = nt_load4(pvA + 64 + q * 4);
        float4 pk0 = nt_load4(pkA + q * 4), pk1 = nt_load4(pkA + 64 + q * 4);

        float4 ia0, ia1, ib0, ib1, um0, um1, x0, x1v;
        bfu(iaP, ia0, ia1);
        bfu(umP, um0, um1);
        float d0 = dot4(um0, ia0) + dot4(um1, ia1);
        float q1 = d0 + dot4(um0, pv0) + dot4(um1, pv1);
        float q2 = d0 + dot4(ia0, pk0) + dot4(ia1, pk1);
        bfu(liP, x0, x1v);
        float q3 = dot4(x0, ia0) + dot4(x1v, ia1);
        bfu(luP, x0, x1v);
        float q4 = dot4(x0, ia0) + dot4(x1v, ia1);
#pragma unroll
        for (int o = 8; o > 0; o >>= 1) {
            q1 += __shfl_xor(q1, o); q2 += __shfl_xor(q2, o);
            q3 += __shfl_xor(q3, o); q4 += __shfl_xor(q4, o);
        }
        float x1 = __expf(q1 * inv_sqrt_d);
        float x2 = __expf(q2 * inv_sqrt_d);
        float x3 = __expf(q3 * inv_sqrt_d);
        float x4 = __expf(q4 * inv_sqrt_d);

        bfu(ibP, ib0, ib1);
        a1l.x += x1*(ib0.x+pk0.x); a1l.y += x1*(ib0.y+pk0.y);
        a1l.z += x1*(ib0.z+pk0.z); a1l.w += x1*(ib0.w+pk0.w);
        a1h.x += x1*(ib1.x+pk1.x); a1h.y += x1*(ib1.y+pk1.y);
        a1h.z += x1*(ib1.z+pk1.z); a1h.w += x1*(ib1.w+pk1.w);
        a3l.x += x3*(ia0.x+1.f);   a3l.y += x3*(ia0.y+1.f);
        a3l.z += x3*(ia0.z+1.f);   a3l.w += x3*(ia0.w+1.f);
        a3h.x += x3*(ia1.x+1.f);   a3h.y += x3*(ia1.y+1.f);
        a3h.z += x3*(ia1.z+1.f);   a3h.w += x3*(ia1.w+1.f);
        s1 += x1; s3 += x3;
        if (q == 0) x24[rA.y] = make_float2(x2, x4);

        eA = eN; vA = vN; rA = rN;
    }
    float r1 = (s1 > 0.f) ? 1.f / s1 : 0.f;
    float r3 = (s3 > 0.f) ? 1.f / s3 : 0.f;
    float4* oL = (float4*)(hLu + (size_t)uid * 128);
    float4* oS = (float4*)(hSu + (size_t)uid * 128);
    oL[q]      = make_float4(a1l.x*r1, a1l.y*r1, a1l.z*r1, a1l.w*r1);
    oL[q + 16] = make_float4(a1h.x*r1, a1h.y*r1, a1h.z*r1, a1h.w*r1);
    oS[q]      = make_float4(a3l.x*r3, a3l.y*r3, a3l.z*r3, a3l.w*r3);
    oS[q + 16] = make_float4(a3h.x*r3, a3h.y*r3, a3h.z*r3, a3h.w*r3);
}

// ----------------------- gather_i: 16-lane group/item, unroll 1, VGPR<=64 ---
__global__ __launch_bounds__(256, 8) void gather_i_kernel(
    const unsigned short* __restrict__ fusedU,   // [U,256] bf16 interleaved
    const float* __restrict__ pVui,
    const int2* __restrict__ lst, const int* __restrict__ off_i,
    const float2* __restrict__ x24,
    float* __restrict__ hLi, float* __restrict__ hSi, int I)
{
    const int wv   = (int)(((size_t)blockIdx.x * blockDim.x + threadIdx.x) >> 6);
    const int lane = threadIdx.x & 63;
    const int g = lane >> 4;
    const int q = lane & 15;
    const int iid = wv * 4 + g;
    if (iid >= I) return;

    float4 a2l = make_float4(0.f,0.f,0.f,0.f), a2h = make_float4(0.f,0.f,0.f,0.f);
    float4 a4l = make_float4(0.f,0.f,0.f,0.f), a4h = make_float4(0.f,0.f,0.f,0.f);
    float s2 = 0.f, s4 = 0.f;
    const int e0 = off_i[iid], e1 = off_i[iid + 1];

    int eA = e0;
    bool vA = eA < e1;
    int2 rA = vA ? lst[eA] : make_int2(0, 0);
    float2 xA = vA ? x24[rA.y] : make_float2(0.f, 0.f);

    while (vA) {
        const int eN = eA + 1;
        const bool vN = eN < e1;
        const int2 rN = vN ? lst[eN] : rA;
        const float2 xN = vN ? x24[rN.y] : make_float2(0.f, 0.f);

        const uint4* fUA = (const uint4*)(fusedU + (size_t)rA.x * 256);
        const float* pvA = pVui + (size_t)rA.y * 128;

        uint4 uaP = fUA[q], ubP = fUA[16 + q];
        float4 pv0 = nt_load4(pvA + q * 4), pv1 = nt_load4(pvA + 64 + q * 4);

        float4 ua0, ua1, ub0, ub1;
        bfu(uaP, ua0, ua1); bfu(ubP, ub0, ub1);

        a2l.x += xA.x*(ub0.x+pv0.x); a2l.y += xA.x*(ub0.y+pv0.y);
        a2l.z += xA.x*(ub0.z+pv0.z); a2l.w += xA.x*(ub0.w+pv0.w);
        a2h.x += xA.x*(ub1.x+pv1.x); a2h.y += xA.x*(ub1.y+pv1.y);
        a2h.z += xA.x*(ub1.z+pv1.z); a2h.w += xA.x*(ub1.w+pv1.w);
        a4l.x += xA.y*(ua0.x+1.f);   a4l.y += xA.y*(ua0.y+1.f);
        a4l.z += xA.y*(ua0.z+1.f);   a4l.w += xA.y*(ua0.w+1.f);
        a4h.x += xA.y*(ua1.x+1.f);   a4h.y += xA.y*(ua1.y+1.f);
        a4h.z += xA.y*(ua1.z+1.f);   a4h.w += xA.y*(ua1.w+1.f);
        s2 += xA.x; s4 += xA.y;

        eA = eN; vA = vN; rA = rN; xA = xN;
    }
    float r2 = (s2 > 0.f) ? 1.f / s2 : 0.f;
    float r4 = (s4 > 0.f) ? 1.f / s4 : 0.f;
    float4* oL = (float4*)(hLi + (size_t)iid * 128);
    float4* oS = (float4*)(hSi + (size_t)iid * 128);
    oL[q]      = make_float4(a2l.x*r2, a2l.y*r2, a2l.z*r2, a2l.w*r2);
    oL[q + 16] = make_float4(a2h.x*r2, a2h.y*r2, a2h.z*r2, a2h.w*r2);
    oS[q]      = make_float4(a4l.x*r4, a4l.y*r4, a4l.z*r4, a4l.w*r4);
    oS[q + 16] = make_float4(a4h.x*r4, a4h.y*r4, a4h.z*r4, a4h.w*r4);
}

// ---------------------------------------------------------------------------
extern "C" void kernel_launch(void* const* d_in, const int* in_sizes, int n_in,
                              void* d_out, int out_size, void* d_ws, size_t ws_size,
                              hipStream_t stream)
{
    const float* u_emb = (const float*)d_in[0];
    const float* i_emb = (const float*)d_in[1];
    const float* pVui  = (const float*)d_in[2];
    const float* pKiu  = (const float*)d_in[3];
    const float* w1    = (const float*)d_in[4];
    const float* w2    = (const float*)d_in[5];
    const float* w1b   = (const float*)d_in[6];
    const float* w2b   = (const float*)d_in[7];
    const float* w3    = (const float*)d_in[8];
    const float* w4    = (const float*)d_in[9];
    const int* edge_index = (const int*)d_in[10];
    const int* last_u     = (const int*)d_in[11];
    const int* last_i     = (const int*)d_in[12];

    const int U = in_sizes[0] / 128;
    const int I = in_sizes[1] / 128;
    const int E = in_sizes[10] / 2;
    const int nbu = (U + WB - 1) / WB;
    const int nbi = (I + WB - 1) / WB;

    unsigned short* us = (unsigned short*)d_ws;
    unsigned short* fusedU    = us;  us += (size_t)U * 256;
    unsigned short* fusedI    = us;  us += (size_t)I * 256;
    unsigned short* last_item = us;  us += (size_t)U * 128;
    unsigned short* last_user = us;  us += (size_t)I * 128;
    float* ws = (float*)us;
    float2* x24 = (float2*)ws;  ws += (size_t)E * 2;
    int2* eu_list = (int2*)ws;  ws += (size_t)E * 2;
    int2* ei_list = (int2*)ws;  ws += (size_t)E * 2;
    int* ip = (int*)ws;
    int* deg_u   = ip;  ip += U;
    int* deg_i   = ip;  ip += I;
    int* off_u   = ip;  ip += U + 1;
    int* off_i   = ip;  ip += I + 1;
    int* cur_u   = ip;  ip += U;
    int* cur_i   = ip;  ip += I;
    int* bsum    = ip;  ip += nbu + nbi;
    int* bscan   = ip;  ip += nbu + nbi;

    float* hLu = (float*)d_out;
    float* hSu = hLu + (size_t)U * 128;
    float* hLi = hSu + (size_t)U * 128;
    float* hSi = hLi + (size_t)I * 128;

    dim3 blk(256);
    const int eblk = (E + 255) / 256;
    zero_kernel<<<(U + I + 255) / 256, blk, 0, stream>>>(deg_u, U + I);
    hist_kernel<<<eblk, blk, 0, stream>>>(edge_index, E, deg_u, deg_i);
    scan_blocksums_kernel<<<nbu + nbi, blk, 0, stream>>>(deg_u, U, nbu, deg_i, I, bsum);
    scan_partials_kernel<<<2, 64, 0, stream>>>(bsum, bscan, nbu, nbi, off_u, U, off_i, I);
    scan_final_kernel<<<nbu + nbi, blk, 0, stream>>>(
        deg_u, U, nbu, deg_i, I, bscan, off_u, cur_u, off_i, cur_i);
    scatter_ids_kernel<<<eblk, blk, 0, stream>>>(
        edge_index, E, cur_u, cur_i, eu_list, ei_list);

    Gemm6Desc gd;
    gd.X[0] = u_emb; gd.W[0] = w2;  gd.O[0] = fusedU;       gd.g[0] = nullptr;    gd.ostride[0] = 256; gd.nrows[0] = U;
    gd.X[1] = u_emb; gd.W[1] = w2b; gd.O[1] = fusedU + 128; gd.g[1] = nullptr;    gd.ostride[1] = 256; gd.nrows[1] = U;
    gd.X[2] = i_emb; gd.W[2] = w1;  gd.O[2] = fusedI;       gd.g[2] = nullptr;    gd.ostride[2] = 256; gd.nrows[2] = I;
    gd.X[3] = i_emb; gd.W[3] = w1b; gd.O[3] = fusedI + 128; gd.g[3] = nullptr;    gd.ostride[3] = 256; gd.nrows[3] = I;
    gd.X[4] = i_emb; gd.W[4] = w3;  gd.O[4] = last_item;    gd.g[4] = last_u + U; gd.ostride[4] = 128; gd.nrows[4] = U;
    gd.X[5] = u_emb; gd.W[5] = w4;  gd.O[5] = last_user;    gd.g[5] = last_i + I; gd.ostride[5] = 128; gd.nrows[5] = I;
    int maxrows = (U > I) ? U : I;
    dim3 ggrid((maxrows + 63) / 64, 6);
    gemm6_kernel<<<ggrid, blk, 0, stream>>>(gd);

    const float inv_sqrt_d = 1.0f / sqrtf(128.0f);
    gather_u_kernel<<<(U + 15) / 16, blk, 0, stream>>>(
        fusedU, fusedI, last_item, last_user, pVui, pKiu, eu_list, off_u,
        x24, hLu, hSu, U, inv_sqrt_d);
    gather_i_kernel<<<(I + 15) / 16, blk, 0, stream>>>(
        fusedU, pVui, ei_list, off_i, x24, hLi, hSi, I);
}

// Round 16
// 706.637 us; speedup vs baseline: 1.4354x; 1.4354x over previous
//
#include <hip/hip_runtime.h>
#include <hip/hip_bf16.h>
#include <math.h>

// ---------------------------------------------------------------------------
// DGSR layer, MI355X. H = 128 fixed.  (round-13 structure + packed hoists)
//   0. zero_kernel: zero degree arrays
//   1. CSR build: histogram -> 3-kernel scan -> scatter of int2 (partner,eid)
//   2. gemm6: fused 6 projections -> interleaved bf16 tables (chunk q =
//      {elems 4q..4q+3, 64+4q..64+4q+3})
//   3. gather_u: 16-lane group per user (4/wave), unroll x2 + record
//      prefetch; hoisted user rows kept PACKED bf16 (target VGPR<=64 for
//      one extra occupancy step WITHOUT the 8-wave cache-thrash regime
//      that round 15 exposed). Writes x24[eid]=(x2,x4).
//   4. gather_i: 16-lane group per item, unroll x2, streaming accumulate.
// exp without max-subtraction (logits ~N(0,1.4)). No f32 atomics anywhere.
// ---------------------------------------------------------------------------

#define WB 1024  // elements per scan block

typedef float fvec4 __attribute__((ext_vector_type(4)));

__device__ __forceinline__ float4 nt_load4(const float* p) {
    fvec4 v = __builtin_nontemporal_load((const fvec4*)p);
    return make_float4(v.x, v.y, v.z, v.w);
}
__device__ __forceinline__ float dot4(float4 a, float4 b) {
    return a.x * b.x + a.y * b.y + a.z * b.z + a.w * b.w;
}
// unpack 8 bf16 (uint4 = one interleaved chunk) -> lo4 (elems 4q..) hi4 (64+4q..)
__device__ __forceinline__ void bfu(uint4 v, float4& lo, float4& hi) {
    lo.x = __uint_as_float(v.x << 16);
    lo.y = __uint_as_float(v.x & 0xFFFF0000u);
    lo.z = __uint_as_float(v.y << 16);
    lo.w = __uint_as_float(v.y & 0xFFFF0000u);
    hi.x = __uint_as_float(v.z << 16);
    hi.y = __uint_as_float(v.z & 0xFFFF0000u);
    hi.z = __uint_as_float(v.w << 16);
    hi.w = __uint_as_float(v.w & 0xFFFF0000u);
}
__device__ __forceinline__ unsigned rne16(float f) {
    unsigned u = __float_as_uint(f);
    return (u + 0x7FFFu + ((u >> 16) & 1u)) >> 16;
}
__device__ __forceinline__ unsigned pack2(float a, float b) {
    return rne16(a) | (rne16(b) << 16);
}

// ----------------------- zeroing -------------------------------------------
__global__ __launch_bounds__(256) void zero_kernel(int* __restrict__ p, int n)
{
    int i = blockIdx.x * 256 + threadIdx.x;
    if (i < n) p[i] = 0;
}

// ----------------------- fused 6x GEMM -> interleaved bf16 tables -----------
struct Gemm6Desc {
    const float* X[6];
    const float* W[6];
    unsigned short* O[6];
    const int*   g[6];
    int          ostride[6];
    int          nrows[6];
};

__global__ __launch_bounds__(256) void gemm6_kernel(Gemm6Desc d)
{
    __shared__ float Xl[64 * 32];
    __shared__ float Wl[128 * 32];
    const int j6 = blockIdx.y;
    const float* __restrict__ X = d.X[j6];
    const float* __restrict__ W = d.W[j6];
    unsigned short* __restrict__ O = d.O[j6];
    const int* __restrict__ gidx = d.g[j6];
    const int ostride = d.ostride[j6];
    const int nrows   = d.nrows[j6];

    const int t  = threadIdx.x;
    const int tx = t & 15;
    const int ty = t >> 4;
    const int brow = blockIdx.x * 64;
    if (brow >= nrows) return;

    float acc[4][8];
#pragma unroll
    for (int j = 0; j < 4; ++j)
#pragma unroll
        for (int i = 0; i < 8; ++i) acc[j][i] = 0.f;

    for (int k0 = 0; k0 < 128; k0 += 32) {
        __syncthreads();
#pragma unroll
        for (int u = 0; u < 2; ++u) {
            int idx4 = t + u * 256;
            int r  = idx4 >> 3;
            int k4 = idx4 & 7;
            int row = brow + r;
            float4 v = make_float4(0.f, 0.f, 0.f, 0.f);
            if (row < nrows) {
                int g = gidx ? gidx[row] : row;
                v = *(const float4*)(X + (size_t)g * 128 + k0 + k4 * 4);
            }
            int sw = k4 ^ ((r >> 3) & 7);
            *(float4*)(Xl + r * 32 + sw * 4) = v;
        }
#pragma unroll
        for (int u = 0; u < 4; ++u) {
            int idx4 = t + u * 256;
            int c  = idx4 >> 3;
            int k4 = idx4 & 7;
            float4 v = *(const float4*)(W + (size_t)c * 128 + k0 + k4 * 4);
            int sw = k4 ^ ((c >> 3) & 7);
            *(float4*)(Wl + c * 32 + sw * 4) = v;
        }
        __syncthreads();
#pragma unroll
        for (int k4 = 0; k4 < 8; ++k4) {
            float4 xv[4], wv[8];
#pragma unroll
            for (int j = 0; j < 4; ++j) {
                int r = ty * 4 + j;
                xv[j] = *(const float4*)(Xl + r * 32 + ((k4 ^ ((r >> 3) & 7)) * 4));
            }
#pragma unroll
            for (int i = 0; i < 8; ++i) {
                int c = tx * 8 + i;
                wv[i] = *(const float4*)(Wl + c * 32 + ((k4 ^ ((c >> 3) & 7)) * 4));
            }
#pragma unroll
            for (int j = 0; j < 4; ++j)
#pragma unroll
                for (int i = 0; i < 8; ++i) {
                    acc[j][i] += xv[j].x * wv[i].x;
                    acc[j][i] += xv[j].y * wv[i].y;
                    acc[j][i] += xv[j].z * wv[i].z;
                    acc[j][i] += xv[j].w * wv[i].w;
                }
        }
    }
    const int base = (tx < 8) ? (16 * tx) : (16 * (tx - 8) + 4);
#pragma unroll
    for (int j = 0; j < 4; ++j) {
        int row = brow + ty * 4 + j;
        if (row < nrows) {
            unsigned short* op = O + (size_t)row * ostride;
            uint2 lo, hi;
            lo.x = pack2(acc[j][0], acc[j][1]);
            lo.y = pack2(acc[j][2], acc[j][3]);
            hi.x = pack2(acc[j][4], acc[j][5]);
            hi.y = pack2(acc[j][6], acc[j][7]);
            *(uint2*)(op + base)     = lo;
            *(uint2*)(op + base + 8) = hi;
        }
    }
}

// ----------------------- CSR build ------------------------------------------
__global__ __launch_bounds__(256) void hist_kernel(
    const int* __restrict__ ei, int E,
    int* __restrict__ deg_u, int* __restrict__ deg_i)
{
    int e = blockIdx.x * 256 + threadIdx.x;
    if (e < E) {
        atomicAdd(&deg_u[ei[e]], 1);
        atomicAdd(&deg_i[ei[E + e]], 1);
    }
}

__global__ __launch_bounds__(256) void scan_blocksums_kernel(
    const int* __restrict__ deg_u, int nu, int nbu,
    const int* __restrict__ deg_i, int ni,
    int* __restrict__ bsum)
{
    int b = blockIdx.x;
    const int* deg; int n; int base;
    if (b < nbu) { deg = deg_u; n = nu; base = b * WB; }
    else         { deg = deg_i; n = ni; base = (b - nbu) * WB; }
    int t = threadIdx.x;
    int s = 0;
#pragma unroll
    for (int j = 0; j < 4; ++j) {
        int i = base + t * 4 + j;
        if (i < n) s += deg[i];
    }
#pragma unroll
    for (int o = 32; o > 0; o >>= 1) s += __shfl_xor(s, o);
    __shared__ int wt[4];
    if ((t & 63) == 0) wt[t >> 6] = s;
    __syncthreads();
    if (t == 0) bsum[b] = wt[0] + wt[1] + wt[2] + wt[3];
}

__global__ void scan_partials_kernel(
    const int* __restrict__ bsum, int* __restrict__ bscan,
    int nbu, int nbi,
    int* __restrict__ off_u, int nu, int* __restrict__ off_i, int ni)
{
    if (threadIdx.x != 0) return;
    if (blockIdx.x == 0) {
        int c = 0;
        for (int b = 0; b < nbu; ++b) { bscan[b] = c; c += bsum[b]; }
        off_u[nu] = c;
    } else {
        int c = 0;
        for (int b = 0; b < nbi; ++b) { bscan[nbu + b] = c; c += bsum[nbu + b]; }
        off_i[ni] = c;
    }
}

__global__ __launch_bounds__(256) void scan_final_kernel(
    const int* __restrict__ deg_u, int nu, int nbu,
    const int* __restrict__ deg_i, int ni,
    const int* __restrict__ bscan,
    int* __restrict__ off_u, int* __restrict__ cur_u,
    int* __restrict__ off_i, int* __restrict__ cur_i)
{
    int b = blockIdx.x;
    const int* deg; int n; int base; int* off; int* cur;
    if (b < nbu) { deg = deg_u; n = nu; base = b * WB; off = off_u; cur = cur_u; }
    else         { deg = deg_i; n = ni; base = (b - nbu) * WB; off = off_i; cur = cur_i; }
    int t = threadIdx.x;
    int lane = t & 63, w = t >> 6;
    int v[4];
    int s = 0;
#pragma unroll
    for (int j = 0; j < 4; ++j) {
        int i = base + t * 4 + j;
        v[j] = (i < n) ? deg[i] : 0;
        s += v[j];
    }
    int inc = s;
#pragma unroll
    for (int o = 1; o < 64; o <<= 1) {
        int x = __shfl_up(inc, o);
        if (lane >= o) inc += x;
    }
    int excl = inc - s;
    __shared__ int wt[4];
    if (lane == 63) wt[w] = inc;
    __syncthreads();
    int wbase = 0;
    for (int j = 0; j < w; ++j) wbase += wt[j];
    int e = bscan[b] + wbase + excl;
#pragma unroll
    for (int j = 0; j < 4; ++j) {
        int i = base + t * 4 + j;
        if (i < n) { off[i] = e; cur[i] = e; }
        e += v[j];
    }
}

__global__ __launch_bounds__(256) void scatter_ids_kernel(
    const int* __restrict__ ei, int E,
    int* __restrict__ cur_u, int* __restrict__ cur_i,
    int2* __restrict__ eu_list, int2* __restrict__ ei_list)
{
    int e = blockIdx.x * 256 + threadIdx.x;
    if (e < E) {
        int u = ei[e], v = ei[E + e];
        int pu = atomicAdd(&cur_u[u], 1);
        eu_list[pu] = make_int2(v, e);   // (item, eid)
        int pi = atomicAdd(&cur_i[v], 1);
        ei_list[pi] = make_int2(u, e);   // (user, eid)
    }
}

// ----------------------- gather_u: 16-lane group per user -------------------
__global__ __launch_bounds__(256) void gather_u_kernel(
    const unsigned short* __restrict__ fusedU,   // [U,256] bf16 interleaved
    const unsigned short* __restrict__ fusedI,   // [I,256] bf16 interleaved
    const unsigned short* __restrict__ last_item,
    const unsigned short* __restrict__ last_user,
    const float* __restrict__ pVui, const float* __restrict__ pKiu,
    const int2* __restrict__ lst, const int* __restrict__ off_u,
    float2* __restrict__ x24,
    float* __restrict__ hLu, float* __restrict__ hSu, int U, float inv_sqrt_d)
{
    const int wv   = (int)(((size_t)blockIdx.x * blockDim.x + threadIdx.x) >> 6);
    const int lane = threadIdx.x & 63;
    const int g = lane >> 4;   // user group within wave
    const int q = lane & 15;   // chunk slot: elems {4q..4q+3, 64+4q..64+4q+3}
    const int uid = wv * 4 + g;
    if (uid >= U) return;

    // hoisted user rows kept PACKED (12 VGPR instead of 24)
    const uint4 umP = ((const uint4*)(fusedU    + (size_t)uid * 256))[q];
    const uint4 liP = ((const uint4*)(last_item + (size_t)uid * 128))[q];
    const uint4 luP = ((const uint4*)(last_user + (size_t)uid * 128))[q];

    float4 a1l = make_float4(0.f,0.f,0.f,0.f), a1h = make_float4(0.f,0.f,0.f,0.f);
    float4 a3l = make_float4(0.f,0.f,0.f,0.f), a3h = make_float4(0.f,0.f,0.f,0.f);
    float s1 = 0.f, s3 = 0.f;
    const int e0 = off_u[uid], e1 = off_u[uid + 1];

    int eA = e0, eB = e0 + 1;
    bool vA = eA < e1, vB = eB < e1;
    int2 rA = vA ? lst[eA] : make_int2(0, 0);
    int2 rB = vB ? lst[eB] : rA;

    while (vA) {
        int eA2 = eA + 2, eB2 = eB + 2;
        bool vA2 = eA2 < e1, vB2 = eB2 < e1;
        int2 rA2 = vA2 ? lst[eA2] : make_int2(0, 0);
        int2 rB2 = vB2 ? lst[eB2] : rA2;

        const uint4* fIA = (const uint4*)(fusedI + (size_t)rA.x * 256);
        const float* pvA = pVui + (size_t)rA.y * 128;
        const float* pkA = pKiu + (size_t)rA.y * 128;
        const uint4* fIB = (const uint4*)(fusedI + (size_t)rB.x * 256);
        const float* pvB = pVui + (size_t)rB.y * 128;
        const float* pkB = pKiu + (size_t)rB.y * 128;

        uint4 iaAp = fIA[q], ibAp = fIA[16 + q];
        uint4 iaBp = fIB[q], ibBp = fIB[16 + q];
        float4 pvA0 = nt_load4(pvA + q * 4), pvA1 = nt_load4(pvA + 64 + q * 4);
        float4 pkA0 = nt_load4(pkA + q * 4), pkA1 = nt_load4(pkA + 64 + q * 4);
        float4 pvB0 = nt_load4(pvB + q * 4), pvB1 = nt_load4(pvB + 64 + q * 4);
        float4 pkB0 = nt_load4(pkB + q * 4), pkB1 = nt_load4(pkB + 64 + q * 4);

        float4 iaA0, iaA1, iaB0, iaB1;
        bfu(iaAp, iaA0, iaA1);
        bfu(iaBp, iaB0, iaB1);

        // unpack um once per iteration (temps die after the dot section)
        float4 t0, t1;
        bfu(umP, t0, t1);
        float dA0 = dot4(t0, iaA0) + dot4(t1, iaA1);
        float qA1 = dA0 + dot4(t0, pvA0) + dot4(t1, pvA1);
        float dB0 = dot4(t0, iaB0) + dot4(t1, iaB1);
        float qB1 = dB0 + dot4(t0, pvB0) + dot4(t1, pvB1);
        float qA2 = dA0 + dot4(iaA0, pkA0) + dot4(iaA1, pkA1);
        float qB2 = dB0 + dot4(iaB0, pkB0) + dot4(iaB1, pkB1);
        bfu(liP, t0, t1);
        float qA3 = dot4(t0, iaA0) + dot4(t1, iaA1);
        float qB3 = dot4(t0, iaB0) + dot4(t1, iaB1);
        bfu(luP, t0, t1);
        float qA4 = dot4(t0, iaA0) + dot4(t1, iaA1);
        float qB4 = dot4(t0, iaB0) + dot4(t1, iaB1);
#pragma unroll
        for (int o = 8; o > 0; o >>= 1) {
            qA1 += __shfl_xor(qA1, o); qA2 += __shfl_xor(qA2, o);
            qA3 += __shfl_xor(qA3, o); qA4 += __shfl_xor(qA4, o);
            qB1 += __shfl_xor(qB1, o); qB2 += __shfl_xor(qB2, o);
            qB3 += __shfl_xor(qB3, o); qB4 += __shfl_xor(qB4, o);
        }
        float x1A = __expf(qA1 * inv_sqrt_d);
        float x2A = __expf(qA2 * inv_sqrt_d);
        float x3A = __expf(qA3 * inv_sqrt_d);
        float x4A = __expf(qA4 * inv_sqrt_d);
        float mB  = vB ? 1.f : 0.f;
        float x1B = __expf(qB1 * inv_sqrt_d) * mB;
        float x2B = __expf(qB2 * inv_sqrt_d);
        float x3B = __expf(qB3 * inv_sqrt_d) * mB;
        float x4B = __expf(qB4 * inv_sqrt_d);

        float4 ibA0, ibA1, ibB0, ibB1;
        bfu(ibAp, ibA0, ibA1);
        bfu(ibBp, ibB0, ibB1);
        a1l.x += x1A*(ibA0.x+pkA0.x) + x1B*(ibB0.x+pkB0.x);
        a1l.y += x1A*(ibA0.y+pkA0.y) + x1B*(ibB0.y+pkB0.y);
        a1l.z += x1A*(ibA0.z+pkA0.z) + x1B*(ibB0.z+pkB0.z);
        a1l.w += x1A*(ibA0.w+pkA0.w) + x1B*(ibB0.w+pkB0.w);
        a1h.x += x1A*(ibA1.x+pkA1.x) + x1B*(ibB1.x+pkB1.x);
        a1h.y += x1A*(ibA1.y+pkA1.y) + x1B*(ibB1.y+pkB1.y);
        a1h.z += x1A*(ibA1.z+pkA1.z) + x1B*(ibB1.z+pkB1.z);
        a1h.w += x1A*(ibA1.w+pkA1.w) + x1B*(ibB1.w+pkB1.w);
        a3l.x += x3A*(iaA0.x+1.f) + x3B*(iaB0.x+1.f);
        a3l.y += x3A*(iaA0.y+1.f) + x3B*(iaB0.y+1.f);
        a3l.z += x3A*(iaA0.z+1.f) + x3B*(iaB0.z+1.f);
        a3l.w += x3A*(iaA0.w+1.f) + x3B*(iaB0.w+1.f);
        a3h.x += x3A*(iaA1.x+1.f) + x3B*(iaB1.x+1.f);
        a3h.y += x3A*(iaA1.y+1.f) + x3B*(iaB1.y+1.f);
        a3h.z += x3A*(iaA1.z+1.f) + x3B*(iaB1.z+1.f);
        a3h.w += x3A*(iaA1.w+1.f) + x3B*(iaB1.w+1.f);
        s1 += x1A + x1B; s3 += x3A + x3B;
        if (q == 0) {
            x24[rA.y] = make_float2(x2A, x4A);
            if (vB) x24[rB.y] = make_float2(x2B, x4B);
        }
        eA = eA2; eB = eB2; vA = vA2; vB = vB2; rA = rA2; rB = rB2;
    }
    float r1 = (s1 > 0.f) ? 1.f / s1 : 0.f;
    float r3 = (s3 > 0.f) ? 1.f / s3 : 0.f;
    float4* oL = (float4*)(hLu + (size_t)uid * 128);
    float4* oS = (float4*)(hSu + (size_t)uid * 128);
    oL[q]      = make_float4(a1l.x*r1, a1l.y*r1, a1l.z*r1, a1l.w*r1);
    oL[q + 16] = make_float4(a1h.x*r1, a1h.y*r1, a1h.z*r1, a1h.w*r1);
    oS[q]      = make_float4(a3l.x*r3, a3l.y*r3, a3l.z*r3, a3l.w*r3);
    oS[q + 16] = make_float4(a3h.x*r3, a3h.y*r3, a3h.z*r3, a3h.w*r3);
}

// ----------------------- gather_i: 16-lane group per item -------------------
__global__ __launch_bounds__(256) void gather_i_kernel(
    const unsigned short* __restrict__ fusedU,   // [U,256] bf16 interleaved
    const float* __restrict__ pVui,
    const int2* __restrict__ lst, const int* __restrict__ off_i,
    const float2* __restrict__ x24,
    float* __restrict__ hLi, float* __restrict__ hSi, int I)
{
    const int wv   = (int)(((size_t)blockIdx.x * blockDim.x + threadIdx.x) >> 6);
    const int lane = threadIdx.x & 63;
    const int g = lane >> 4;
    const int q = lane & 15;
    const int iid = wv * 4 + g;
    if (iid >= I) return;

    float4 a2l = make_float4(0.f,0.f,0.f,0.f), a2h = make_float4(0.f,0.f,0.f,0.f);
    float4 a4l = make_float4(0.f,0.f,0.f,0.f), a4h = make_float4(0.f,0.f,0.f,0.f);
    float s2 = 0.f, s4 = 0.f;
    const int e0 = off_i[iid], e1 = off_i[iid + 1];

    int eA = e0, eB = e0 + 1;
    bool vA = eA < e1, vB = eB < e1;
    int2 rA = vA ? lst[eA] : make_int2(0, 0);
    int2 rB = vB ? lst[eB] : rA;
    float2 xA = vA ? x24[rA.y] : make_float2(0.f, 0.f);
    float2 xB = vB ? x24[rB.y] : make_float2(0.f, 0.f);

    while (vA) {
        int eA2 = eA + 2, eB2 = eB + 2;
        bool vA2 = eA2 < e1, vB2 = eB2 < e1;
        int2 rA2 = vA2 ? lst[eA2] : make_int2(0, 0);
        int2 rB2 = vB2 ? lst[eB2] : rA2;
        float2 xA2v = vA2 ? x24[rA2.y] : make_float2(0.f, 0.f);
        float2 xB2v = vB2 ? x24[rB2.y] : make_float2(0.f, 0.f);

        const uint4* fUA = (const uint4*)(fusedU + (size_t)rA.x * 256);
        const float* pvA = pVui + (size_t)rA.y * 128;
        const uint4* fUB = (const uint4*)(fusedU + (size_t)rB.x * 256);
        const float* pvB = pVui + (size_t)rB.y * 128;

        uint4 uaAp = fUA[q], ubAp = fUA[16 + q];
        uint4 uaBp = fUB[q], ubBp = fUB[16 + q];
        float4 pvA0 = nt_load4(pvA + q * 4), pvA1 = nt_load4(pvA + 64 + q * 4);
        float4 pvB0 = nt_load4(pvB + q * 4), pvB1 = nt_load4(pvB + 64 + q * 4);

        float4 uaA0, uaA1, ubA0, ubA1, uaB0, uaB1, ubB0, ubB1;
        bfu(uaAp, uaA0, uaA1); bfu(ubAp, ubA0, ubA1);
        bfu(uaBp, uaB0, uaB1); bfu(ubBp, ubB0, ubB1);

        if (!vB) { xB.x = 0.f; xB.y = 0.f; }
        a2l.x += xA.x*(ubA0.x+pvA0.x) + xB.x*(ubB0.x+pvB0.x);
        a2l.y += xA.x*(ubA0.y+pvA0.y) + xB.x*(ubB0.y+pvB0.y);
        a2l.z += xA.x*(ubA0.z+pvA0.z) + xB.x*(ubB0.z+pvB0.z);
        a2l.w += xA.x*(ubA0.w+pvA0.w) + xB.x*(ubB0.w+pvB0.w);
        a2h.x += xA.x*(ubA1.x+pvA1.x) + xB.x*(ubB1.x+pvB1.x);
        a2h.y += xA.x*(ubA1.y+pvA1.y) + xB.x*(ubB1.y+pvB1.y);
        a2h.z += xA.x*(ubA1.z+pvA1.z) + xB.x*(ubB1.z+pvB1.z);
        a2h.w += xA.x*(ubA1.w+pvA1.w) + xB.x*(ubB1.w+pvB1.w);
        a4l.x += xA.y*(uaA0.x+1.f) + xB.y*(uaB0.x+1.f);
        a4l.y += xA.y*(uaA0.y+1.f) + xB.y*(uaB0.y+1.f);
        a4l.z += xA.y*(uaA0.z+1.f) + xB.y*(uaB0.z+1.f);
        a4l.w += xA.y*(uaA0.w+1.f) + xB.y*(uaB0.w+1.f);
        a4h.x += xA.y*(uaA1.x+1.f) + xB.y*(uaB1.x+1.f);
        a4h.y += xA.y*(uaA1.y+1.f) + xB.y*(uaB1.y+1.f);
        a4h.z += xA.y*(uaA1.z+1.f) + xB.y*(uaB1.z+1.f);
        a4h.w += xA.y*(uaA1.w+1.f) + xB.y*(uaB1.w+1.f);
        s2 += xA.x + xB.x; s4 += xA.y + xB.y;

        eA = eA2; eB = eB2; vA = vA2; vB = vB2;
        rA = rA2; rB = rB2; xA = xA2v; xB = xB2v;
    }
    float r2 = (s2 > 0.f) ? 1.f / s2 : 0.f;
    float r4 = (s4 > 0.f) ? 1.f / s4 : 0.f;
    float4* oL = (float4*)(hLi + (size_t)iid * 128);
    float4* oS = (float4*)(hSi + (size_t)iid * 128);
    oL[q]      = make_float4(a2l.x*r2, a2l.y*r2, a2l.z*r2, a2l.w*r2);
    oL[q + 16] = make_float4(a2h.x*r2, a2h.y*r2, a2h.z*r2, a2h.w*r2);
    oS[q]      = make_float4(a4l.x*r4, a4l.y*r4, a4l.z*r4, a4l.w*r4);
    oS[q + 16] = make_float4(a4h.x*r4, a4h.y*r4, a4h.z*r4, a4h.w*r4);
}

// ---------------------------------------------------------------------------
extern "C" void kernel_launch(void* const* d_in, const int* in_sizes, int n_in,
                              void* d_out, int out_size, void* d_ws, size_t ws_size,
                              hipStream_t stream)
{
    const float* u_emb = (const float*)d_in[0];
    const float* i_emb = (const float*)d_in[1];
    const float* pVui  = (const float*)d_in[2];
    const float* pKiu  = (const float*)d_in[3];
    const float* w1    = (const float*)d_in[4];
    const float* w2    = (const float*)d_in[5];
    const float* w1b   = (const float*)d_in[6];
    const float* w2b   = (const float*)d_in[7];
    const float* w3    = (const float*)d_in[8];
    const float* w4    = (const float*)d_in[9];
    const int* edge_index = (const int*)d_in[10];
    const int* last_u     = (const int*)d_in[11];
    const int* last_i     = (const int*)d_in[12];

    const int U = in_sizes[0] / 128;
    const int I = in_sizes[1] / 128;
    const int E = in_sizes[10] / 2;
    const int nbu = (U + WB - 1) / WB;
    const int nbi = (I + WB - 1) / WB;

    unsigned short* us = (unsigned short*)d_ws;
    unsigned short* fusedU    = us;  us += (size_t)U * 256;
    unsigned short* fusedI    = us;  us += (size_t)I * 256;
    unsigned short* last_item = us;  us += (size_t)U * 128;
    unsigned short* last_user = us;  us += (size_t)I * 128;
    float* ws = (float*)us;
    float2* x24 = (float2*)ws;  ws += (size_t)E * 2;
    int2* eu_list = (int2*)ws;  ws += (size_t)E * 2;
    int2* ei_list = (int2*)ws;  ws += (size_t)E * 2;
    int* ip = (int*)ws;
    int* deg_u   = ip;  ip += U;
    int* deg_i   = ip;  ip += I;
    int* off_u   = ip;  ip += U + 1;
    int* off_i   = ip;  ip += I + 1;
    int* cur_u   = ip;  ip += U;
    int* cur_i   = ip;  ip += I;
    int* bsum    = ip;  ip += nbu + nbi;
    int* bscan   = ip;  ip += nbu + nbi;

    float* hLu = (float*)d_out;
    float* hSu = hLu + (size_t)U * 128;
    float* hLi = hSu + (size_t)U * 128;
    float* hSi = hLi + (size_t)I * 128;

    dim3 blk(256);
    const int eblk = (E + 255) / 256;
    zero_kernel<<<(U + I + 255) / 256, blk, 0, stream>>>(deg_u, U + I);
    hist_kernel<<<eblk, blk, 0, stream>>>(edge_index, E, deg_u, deg_i);
    scan_blocksums_kernel<<<nbu + nbi, blk, 0, stream>>>(deg_u, U, nbu, deg_i, I, bsum);
    scan_partials_kernel<<<2, 64, 0, stream>>>(bsum, bscan, nbu, nbi, off_u, U, off_i, I);
    scan_final_kernel<<<nbu + nbi, blk, 0, stream>>>(
        deg_u, U, nbu, deg_i, I, bscan, off_u, cur_u, off_i, cur_i);
    scatter_ids_kernel<<<eblk, blk, 0, stream>>>(
        edge_index, E, cur_u, cur_i, eu_list, ei_list);

    Gemm6Desc gd;
    gd.X[0] = u_emb; gd.W[0] = w2;  gd.O[0] = fusedU;       gd.g[0] = nullptr;    gd.ostride[0] = 256; gd.nrows[0] = U;
    gd.X[1] = u_emb; gd.W[1] = w2b; gd.O[1] = fusedU + 128; gd.g[1] = nullptr;    gd.ostride[1] = 256; gd.nrows[1] = U;
    gd.X[2] = i_emb; gd.W[2] = w1;  gd.O[2] = fusedI;       gd.g[2] = nullptr;    gd.ostride[2] = 256; gd.nrows[2] = I;
    gd.X[3] = i_emb; gd.W[3] = w1b; gd.O[3] = fusedI + 128; gd.g[3] = nullptr;    gd.ostride[3] = 256; gd.nrows[3] = I;
    gd.X[4] = i_emb; gd.W[4] = w3;  gd.O[4] = last_item;    gd.g[4] = last_u + U; gd.ostride[4] = 128; gd.nrows[4] = U;
    gd.X[5] = u_emb; gd.W[5] = w4;  gd.O[5] = last_user;    gd.g[5] = last_i + I; gd.ostride[5] = 128; gd.nrows[5] = I;
    int maxrows = (U > I) ? U : I;
    dim3 ggrid((maxrows + 63) / 64, 6);
    gemm6_kernel<<<ggrid, blk, 0, stream>>>(gd);

    const float inv_sqrt_d = 1.0f / sqrtf(128.0f);
    gather_u_kernel<<<(U + 15) / 16, blk, 0, stream>>>(
        fusedU, fusedI, last_item, last_user, pVui, pKiu, eu_list, off_u,
        x24, hLu, hSu, U, inv_sqrt_d);
    gather_i_kernel<<<(I + 15) / 16, blk, 0, stream>>>(
        fusedU, pVui, ei_list, off_i, x24, hLi, hSi, I);
}